// Round 6
// baseline (539.519 us; speedup 1.0000x reference)
//
#include <hip/hip_runtime.h>
#include <cstdint>
#include <cstddef>

#define T_SEQ 2048
#define B_SZ  8
#define F_DIM 768
#define H_CNT 3
#define DH    256
#define WSZ   (F_DIM * F_DIM)

typedef float floatx4 __attribute__((ext_vector_type(4)));
typedef short bf16x8  __attribute__((ext_vector_type(8)));

// round-half-up f32->bf16
static __device__ __forceinline__ unsigned short f2bf(float f) {
    union { float f; unsigned int i; } x; x.f = f;
    return (unsigned short)((x.i + 0x8000u) >> 16);
}
// pack two f32 -> u32 of two bf16 (lo=a, hi=b)
static __device__ __forceinline__ unsigned int pkbf(float a, float b) {
    union { float f; unsigned int i; } xa, xb; xa.f = a; xb.f = b;
    return __builtin_amdgcn_perm(xb.i + 0x8000u, xa.i + 0x8000u, 0x07060302u);
}

// async global->LDS, 16B per lane; LDS dest = wave-uniform base + lane*16
#define ASYNC16(g, l) __builtin_amdgcn_global_load_lds( \
    (__attribute__((address_space(1))) void*)(void*)(g), \
    (__attribute__((address_space(3))) void*)(l), 16, 0, 0)

// ---------------------------------------------------------------------------
// One-shot fp32 -> bf16 convert: x (E elems) then Wq,Wk,Wv,Wo (WSZ each).
// ---------------------------------------------------------------------------
__global__ void cvt_bf16(const float* __restrict__ x,
                         const float* __restrict__ wq,
                         const float* __restrict__ wk,
                         const float* __restrict__ wv,
                         const float* __restrict__ wo,
                         unsigned short* __restrict__ dst)
{
    const size_t E = (size_t)T_SEQ * B_SZ * F_DIM;
    const size_t tot8 = (E + 4 * (size_t)WSZ) / 8;
    for (size_t i = (size_t)blockIdx.x * blockDim.x + threadIdx.x; i < tot8;
         i += (size_t)gridDim.x * blockDim.x) {
        const size_t e = i * 8;
        const float* src; size_t off;
        if (e < E)                        { src = x;  off = e; }
        else if (e < E + WSZ)             { src = wq; off = e - E; }
        else if (e < E + 2 * (size_t)WSZ) { src = wk; off = e - E - WSZ; }
        else if (e < E + 3 * (size_t)WSZ) { src = wv; off = e - E - 2 * (size_t)WSZ; }
        else                              { src = wo; off = e - E - 3 * (size_t)WSZ; }
        const floatx4 a = *(const floatx4*)(src + off);
        const floatx4 b = *(const floatx4*)(src + off + 4);
        union { unsigned int u[4]; bf16x8 v; } r;
        r.u[0] = pkbf(a[0], a[1]); r.u[1] = pkbf(a[2], a[3]);
        r.u[2] = pkbf(b[0], b[1]); r.u[3] = pkbf(b[2], b[3]);
        *(bf16x8*)(dst + e) = r.v;
    }
}

// ---------------------------------------------------------------------------
// Pure-bf16 NT GEMM, m97 recipe: 128x128 tile, BK=32, async LDS staging for
// BOTH operands. MODE 1: QKV-fused (blockIdx.z selects W/bias/scale and the
// fragment-layout epilogue). MODE 0: out-proj, C fp32 row-major + bias.
// ---------------------------------------------------------------------------
template<int MODE>
__global__ __launch_bounds__(256, 2) void gemm_bf16(
    const unsigned short* __restrict__ A,    // (M,K) bf16
    const unsigned short* __restrict__ Wb,   // MODE1: Wq|Wk|Wv concat; MODE0: Wo
    const float* __restrict__ b0,
    const float* __restrict__ b1,
    const float* __restrict__ b2,
    void* __restrict__ Cv,
    int M, int N, int K)
{
    __shared__ __align__(16) unsigned short As[128 * 32];
    __shared__ __align__(16) unsigned short Bs[128 * 32];

    const int z    = (MODE == 1) ? blockIdx.z : 0;
    const unsigned short* W = Wb + (size_t)z * WSZ;
    const float* bias = (MODE == 1) ? (z == 0 ? b0 : (z == 1 ? b1 : b2)) : b0;
    const float scale = (MODE == 1 && z == 0) ? 0.125f : 1.0f;

    const int tid  = threadIdx.x;
    const int wave = tid >> 6;
    const int lane = tid & 63;
    const int m0 = blockIdx.y * 128;
    const int n0 = blockIdx.x * 128;
    const int wm = (wave >> 1) * 64;
    const int wn = (wave & 1) * 64;
    const int q4 = lane >> 4;
    const int rr = lane & 15;

    const int lrow = lane >> 2;
    const int lk8  = (lane & 3) * 8;
    const int ar0 = wave * 16 + lrow;
    const int ar1 = (wave + 4) * 16 + lrow;

    floatx4 acc[4][4];
#pragma unroll
    for (int i = 0; i < 4; ++i)
#pragma unroll
        for (int j = 0; j < 4; ++j) acc[i][j] = (floatx4)0.0f;

    for (int k0 = 0; k0 < K; k0 += 32) {
        __syncthreads();   // previous iteration's fragment reads complete
        ASYNC16(A + (size_t)(m0 + ar0) * K + k0 + lk8, (unsigned short*)As + wave * 512);
        ASYNC16(A + (size_t)(m0 + ar1) * K + k0 + lk8, (unsigned short*)As + (wave + 4) * 512);
        ASYNC16(W + (size_t)(n0 + ar0) * K + k0 + lk8, (unsigned short*)Bs + wave * 512);
        ASYNC16(W + (size_t)(n0 + ar1) * K + k0 + lk8, (unsigned short*)Bs + (wave + 4) * 512);
        __syncthreads();   // vmcnt drain: tiles valid

        bf16x8 af[4], bfv[4];
#pragma unroll
        for (int mt = 0; mt < 4; ++mt)
            af[mt] = *(const bf16x8*)&As[(wm + mt * 16 + rr) * 32 + q4 * 8];
#pragma unroll
        for (int nt = 0; nt < 4; ++nt)
            bfv[nt] = *(const bf16x8*)&Bs[(wn + nt * 16 + rr) * 32 + q4 * 8];
#pragma unroll
        for (int mt = 0; mt < 4; ++mt)
#pragma unroll
            for (int nt = 0; nt < 4; ++nt)
                acc[mt][nt] = __builtin_amdgcn_mfma_f32_16x16x32_bf16(af[mt], bfv[nt], acc[mt][nt], 0, 0, 0);
    }

#pragma unroll
    for (int nt = 0; nt < 4; ++nt) {
        const int col = n0 + wn + nt * 16 + rr;
        const float bv = bias[col];
#pragma unroll
        for (int mt = 0; mt < 4; ++mt) {
#pragma unroll
            for (int r = 0; r < 4; ++r) {
                const int row = m0 + wm + mt * 16 + q4 * 4 + r;
                const float v = (acc[mt][nt][r] + bv) * scale;
                if (MODE == 0) {
                    ((float*)Cv)[(size_t)row * N + col] = v;
                } else {
                    const int t = row >> 3, bb = row & 7;   // row = t*B + b
                    const int h = col >> 8, d = col & 255;  // col = h*256 + d
                    const size_t hb = (size_t)(bb * H_CNT + h) * (T_SEQ * DH);
                    size_t idx;
                    if (z < 2) {   // QK-fragment layout
                        const int sblk = t >> 4, rrq = t & 15;
                        const int kc = d >> 5, q4v = (d >> 3) & 3, e = d & 7;
                        idx = hb + (size_t)(((sblk * 8 + kc) * 64 + q4v * 16 + rrq) * 8 + e);
                    } else {       // V-fragment layout
                        const int skc = t >> 5, q4v = (t >> 3) & 3, e = t & 7;
                        const int dblk = d >> 4, rrq = d & 15;
                        idx = hb + (size_t)(((skc * 16 + dblk) * 64 + q4v * 16 + rrq) * 8 + e);
                    }
                    ((unsigned short*)Cv + (size_t)z * ((size_t)T_SEQ * B_SZ * F_DIM))[idx] = f2bf(v);
                }
            }
        }
    }
}

// ---------------------------------------------------------------------------
// Flash attention v3: async double-buffered K/V, ONE barrier per 32-s chunk.
// grid (T/64, B*H), 128 threads (2 waves), 32 Q rows/wave, S^T = K Q^T
// orientation (softmax in-reg), O^T = V^T P. 68 KB LDS -> 2 blocks/CU.
// Pipeline: sync(drain stage i) -> issue stage(i+1) -> compute(i); staged
// loads stay in flight across the whole compute phase.
// ---------------------------------------------------------------------------
__global__ __launch_bounds__(128, 2) void attn_kernel(
    const unsigned short* __restrict__ Qf,
    const unsigned short* __restrict__ Kf,
    const unsigned short* __restrict__ Vf,
    unsigned short* __restrict__ Ob)
{
    __shared__ __align__(16) unsigned short Ks[2][8192];     // [sblk2][kc8][64][8]
    __shared__ __align__(16) unsigned short Vs[2][8192];     // [dblk16][64][8]
    __shared__ __align__(16) unsigned short Ps[2][32 * 40];  // per-wave P[q][s]

    const int tid  = threadIdx.x;
    const int wave = tid >> 6;
    const int lane = tid & 63;
    const int q4 = lane >> 4;
    const int rr = lane & 15;
    const int bh = blockIdx.y;
    const int b  = bh / H_CNT;
    const int h  = bh % H_CNT;
    const size_t hb = (size_t)bh * (T_SEQ * DH);

    // wave's 32 Q rows = two 16-row fragment tiles (prescaled by 1/8)
    const int sb0 = blockIdx.x * 4 + wave * 2;
    bf16x8 qf_[2][8];
#pragma unroll
    for (int qnt = 0; qnt < 2; ++qnt)
#pragma unroll
        for (int kc = 0; kc < 8; ++kc)
            qf_[qnt][kc] = *(const bf16x8*)(Qf + hb + ((size_t)((sb0 + qnt) * 8 + kc) * 64 + lane) * 8);

    float m_[2] = { -1e9f, -1e9f }, l_[2] = { 0.0f, 0.0f };
    floatx4 oacc[16][2];
#pragma unroll
    for (int dt = 0; dt < 16; ++dt)
#pragma unroll
        for (int qnt = 0; qnt < 2; ++qnt) oacc[dt][qnt] = (floatx4)0.0f;

    const unsigned short* kg = Kf + hb;
    const unsigned short* vg = Vf + hb;
    const int so = wave * 4096 + lane * 8;   // staging offset (elems)

    // prologue: stage chunk 0 into buffer 0
#pragma unroll
    for (int rnd = 0; rnd < 8; ++rnd) {
        ASYNC16(kg + so + rnd * 512, (unsigned short*)Ks[0] + wave * 4096 + rnd * 512);
        ASYNC16(vg + so + rnd * 512, (unsigned short*)Vs[0] + wave * 4096 + rnd * 512);
    }

    for (int i = 0; i < 64; ++i) {
        __syncthreads();   // drains stage(i) (vmcnt 0) + joins waves
        const int cur = i & 1;
        if (i < 63) {      // issue stage(i+1) into the other buffer — stays in flight
            const unsigned short* kg2 = kg + (size_t)(i + 1) * 8192;
            const unsigned short* vg2 = vg + (size_t)(i + 1) * 8192;
#pragma unroll
            for (int rnd = 0; rnd < 8; ++rnd) {
                ASYNC16(kg2 + so + rnd * 512, (unsigned short*)Ks[cur ^ 1] + wave * 4096 + rnd * 512);
                ASYNC16(vg2 + so + rnd * 512, (unsigned short*)Vs[cur ^ 1] + wave * 4096 + rnd * 512);
            }
        }

        // S^T = K Q^T : D[s][q], tiles [smt][qnt]
        floatx4 sacc[2][2];
#pragma unroll
        for (int a = 0; a < 2; ++a)
#pragma unroll
            for (int c = 0; c < 2; ++c) sacc[a][c] = (floatx4)0.0f;
#pragma unroll
        for (int kc = 0; kc < 8; ++kc) {
            bf16x8 k0 = *(const bf16x8*)&Ks[cur][((0 * 8 + kc) * 64 + lane) * 8];
            bf16x8 k1 = *(const bf16x8*)&Ks[cur][((1 * 8 + kc) * 64 + lane) * 8];
            sacc[0][0] = __builtin_amdgcn_mfma_f32_16x16x32_bf16(k0, qf_[0][kc], sacc[0][0], 0, 0, 0);
            sacc[0][1] = __builtin_amdgcn_mfma_f32_16x16x32_bf16(k0, qf_[1][kc], sacc[0][1], 0, 0, 0);
            sacc[1][0] = __builtin_amdgcn_mfma_f32_16x16x32_bf16(k1, qf_[0][kc], sacc[1][0], 0, 0, 0);
            sacc[1][1] = __builtin_amdgcn_mfma_f32_16x16x32_bf16(k1, qf_[1][kc], sacc[1][1], 0, 0, 0);
        }

        // online softmax: per lane q-col = qnt*16+rr; 8 s-values in regs
        float alpha[2];
        int upd = 0;
#pragma unroll
        for (int qnt = 0; qnt < 2; ++qnt) {
            float cm = sacc[0][qnt][0];
#pragma unroll
            for (int smt = 0; smt < 2; ++smt)
#pragma unroll
                for (int r = 0; r < 4; ++r) cm = fmaxf(cm, sacc[smt][qnt][r]);
            cm = fmaxf(cm, __shfl_xor(cm, 16));
            cm = fmaxf(cm, __shfl_xor(cm, 32));
            const float mn = fmaxf(m_[qnt], cm);
            alpha[qnt] = __expf(m_[qnt] - mn);
            float rs = 0.0f;
#pragma unroll
            for (int smt = 0; smt < 2; ++smt)
#pragma unroll
                for (int r = 0; r < 4; ++r) {
                    const float p = __expf(sacc[smt][qnt][r] - mn);
                    sacc[smt][qnt][r] = p; rs += p;
                }
            rs += __shfl_xor(rs, 16);
            rs += __shfl_xor(rs, 32);
            l_[qnt] = alpha[qnt] * l_[qnt] + rs;
            upd |= (mn > m_[qnt]);
            m_[qnt] = mn;
        }

        // P (S^T C-layout) -> per-wave LDS tile P[q][s] (stride 40)
        unsigned short* pw = Ps[wave];
#pragma unroll
        for (int qnt = 0; qnt < 2; ++qnt)
#pragma unroll
            for (int smt = 0; smt < 2; ++smt)
#pragma unroll
                for (int r = 0; r < 4; ++r)
                    pw[(qnt * 16 + rr) * 40 + smt * 16 + q4 * 4 + r] = f2bf(sacc[smt][qnt][r]);
        bf16x8 pf0 = *(const bf16x8*)&pw[(0 * 16 + rr) * 40 + q4 * 8];
        bf16x8 pf1 = *(const bf16x8*)&pw[(1 * 16 + rr) * 40 + q4 * 8];

        if (__any(upd)) {
#pragma unroll
            for (int dt = 0; dt < 16; ++dt)
#pragma unroll
                for (int qnt = 0; qnt < 2; ++qnt)
#pragma unroll
                    for (int r = 0; r < 4; ++r) oacc[dt][qnt][r] *= alpha[qnt];
        }

        // O^T += V^T P
#pragma unroll
        for (int dt = 0; dt < 16; ++dt) {
            bf16x8 vf = *(const bf16x8*)&Vs[cur][(dt * 64 + lane) * 8];
            oacc[dt][0] = __builtin_amdgcn_mfma_f32_16x16x32_bf16(vf, pf0, oacc[dt][0], 0, 0, 0);
            oacc[dt][1] = __builtin_amdgcn_mfma_f32_16x16x32_bf16(vf, pf1, oacc[dt][1], 0, 0, 0);
        }
    }

    // epilogue: lane holds (d = dt*16+q4*4+r, q = qnt*16+rr)
#pragma unroll
    for (int qnt = 0; qnt < 2; ++qnt) {
        const float inv_l = 1.0f / fmaxf(l_[qnt], 1e-30f);
        const int t = blockIdx.x * 64 + wave * 32 + qnt * 16 + rr;
        unsigned short* orow = Ob + (size_t)(t * B_SZ + b) * F_DIM + h * DH;
#pragma unroll
        for (int dt = 0; dt < 16; ++dt) {
#pragma unroll
            for (int rp = 0; rp < 2; ++rp) {
                const unsigned int w = pkbf(oacc[dt][qnt][rp * 2] * inv_l,
                                            oacc[dt][qnt][rp * 2 + 1] * inv_l);
                *(unsigned int*)(orow + dt * 16 + q4 * 4 + rp * 2) = w;
            }
        }
    }
}

// ---------------------------------------------------------------------------
extern "C" void kernel_launch(void* const* d_in, const int* in_sizes, int n_in,
                              void* d_out, int out_size, void* d_ws, size_t ws_size,
                              hipStream_t stream)
{
    const float* x  = (const float*)d_in[0];
    const float* Wq = (const float*)d_in[1];
    const float* bq = (const float*)d_in[2];
    const float* Wk = (const float*)d_in[3];
    const float* bk = (const float*)d_in[4];
    const float* Wv = (const float*)d_in[5];
    const float* bv = (const float*)d_in[6];
    const float* Wo = (const float*)d_in[7];
    const float* bo = (const float*)d_in[8];
    float* out = (float*)d_out;

    const int M = T_SEQ * B_SZ;   // 16384
    const int N = F_DIM, K = F_DIM;
    const size_t E = (size_t)M * F_DIM;

    // ws layout: Qf | Kb | Vb | Ob | xb | W16(Wq,Wk,Wv,Wo)
    unsigned short* Qf  = (unsigned short*)d_ws;  // frag-layout Q (prescaled)
    unsigned short* Kb  = Qf + E;                 // frag-layout K
    unsigned short* Vb  = Kb + E;                 // frag-layout V
    unsigned short* Ob  = Vb + E;                 // attn out, row-major bf16
    unsigned short* xb  = Ob + E;                 // x, bf16 (M,K)
    unsigned short* W16 = xb + E;                 // 4 weights bf16, concat

    cvt_bf16<<<dim3(1024), dim3(256), 0, stream>>>(x, Wq, Wk, Wv, Wo, xb);
    gemm_bf16<1><<<dim3(N / 128, M / 128, 3), dim3(256), 0, stream>>>(
        xb, W16, bq, bk, bv, Qf, M, N, K);
    attn_kernel<<<dim3(T_SEQ / 64, B_SZ * H_CNT), dim3(128), 0, stream>>>(Qf, Kb, Vb, Ob);
    gemm_bf16<0><<<dim3(N / 128, M / 128), dim3(256), 0, stream>>>(
        Ob, W16 + (size_t)3 * WSZ, bo, bo, bo, out, M, N, K);
}